// Round 3
// baseline (659.018 us; speedup 1.0000x reference)
//
#include <hip/hip_runtime.h>

// Problem constants (fixed by reference setup_inputs)
constexpr int B = 4, N = 16384, Q = 4096, C = 64, S = 32;

// Kernel 1: transpose features (B,C,N) -> (B,N,C) so per-sample gathers are contiguous.
// Ends with a device-scope fence: on gfx950 the per-XCD L2s are not cross-coherent,
// and graph-replayed dispatches may not re-issue the dispatch-boundary cache ops —
// so we explicitly write back dirty ft lines to the coherence point (buffer_wbl2 sc1).
__global__ __launch_bounds__(256) void transpose_feat(const float* __restrict__ f,
                                                      float* __restrict__ ft) {
    __shared__ float tile[64 * 65];
    const int b  = blockIdx.x / (N / 64);
    const int n0 = (blockIdx.x % (N / 64)) * 64;
    const int t  = threadIdx.x;
    const int nl = t & 63;          // local n
    const int cl = t >> 6;          // 0..3
    const float* fb = f + (size_t)b * C * N;
#pragma unroll
    for (int i = 0; i < 16; ++i) {
        int c = i * 4 + cl;
        tile[c * 65 + nl] = fb[(size_t)c * N + n0 + nl];   // 256B coalesced per c
    }
    __syncthreads();
    float* ftb = ft + ((size_t)b * N + n0) * C;
    const int co = t & 63;
#pragma unroll
    for (int i = 0; i < 16; ++i) {
        int n = i * 4 + (t >> 6);
        ftb[(size_t)n * C + co] = tile[co * 65 + n];       // 256B coalesced per n
    }
    __threadfence();   // device-scope release: drain ft to L3 before block retires
}

// Kernel 2: one wave (64 lanes) per query. Phase 1: ordered ballot ball-query with
// FLOAT64 membership decision (matches the harness's numpy-f64 reference; f64
// roundoff ~1e-16 is far below the min |d2-R2| gap, so formula/order-proof).
// Phase 2: device-scope acquire fence (invalidate stale local-L2 lines, e.g. the
// 0xAA poison), then gather + coalesced write of grouped_xyz and grouped_features.
template <bool USE_T>
__global__ __launch_bounds__(256) void ballgroup(const float* __restrict__ q_xyz,
                                                 const float* __restrict__ s_xyz,
                                                 const float* __restrict__ feat,
                                                 const float* __restrict__ feat_t,
                                                 float* __restrict__ out) {
    __shared__ int   idx_s[4][S];
    __shared__ float tile[4][S * 65];

    const int t    = threadIdx.x;
    const int lane = t & 63;
    const int wid  = t >> 6;
    const int gq   = blockIdx.x * 4 + wid;       // global query id, 0..B*Q-1
    const int b    = gq >> 12;                   // Q = 4096
    const int q    = gq & (Q - 1);

    const float* qp = q_xyz + ((size_t)b * Q + q) * 3;
    const float qx = qp[0], qy = qp[1], qz = qp[2];
    const double qxd = (double)qx, qyd = (double)qy, qzd = (double)qz;
    const double R2D = 0.2 * 0.2;   // IEEE double product = python's radius*radius

    const float* sb = s_xyz + (size_t)b * N * 3;

    int cnt = 0;                                            // wave-uniform
    for (int base = 0; base < N && cnt < S; base += 64) {
        const int n = base + lane;
        const double dx = (double)sb[n * 3 + 0] - qxd;
        const double dy = (double)sb[n * 3 + 1] - qyd;
        const double dz = (double)sb[n * 3 + 2] - qzd;
        const double d2 = dx * dx + dy * dy + dz * dz;      // exact to ~1e-16
        const bool in = d2 < R2D;
        const unsigned long long m = __ballot(in);
        if (in) {
            const int pos = cnt + __popcll(m & ((1ull << lane) - 1ull));
            if (pos < S) idx_s[wid][pos] = n;
        }
        cnt += __popcll(m);
    }
    if (cnt > S) cnt = S;

    __syncthreads();
    const int idx0 = (cnt > 0) ? idx_s[wid][0] : 0;
    if (lane < S && lane >= cnt) idx_s[wid][lane] = idx0;  // pad with first found (or 0)
    __syncthreads();

    // grouped_xyz: (B,3,Q,S) = support[idx] - query  (single f32 sub: bit-exact)
    for (int e = lane; e < 3 * S; e += 64) {
        const int c  = e >> 5;
        const int sI = e & 31;
        const int id = idx_s[wid][sI];
        out[(((size_t)b * 3 + c) * Q + q) * S + sI] = sb[id * 3 + c] - qp[c];
    }

    // Device-scope acquire: invalidate any stale (poisoned) ft lines in this XCD's
    // L2 before reading the other kernel's output. Graph-replay dispatch boundaries
    // are not trusted to do this (per-XCD L2 non-coherence, Guideline 16).
    if (USE_T) __threadfence();

    // gather feature rows into LDS tile (tile[s][c], stride 65: conflict-free)
    if (USE_T) {
        const float* ftb = feat_t + (size_t)b * N * C;
        for (int sI = 0; sI < S; ++sI) {
            const int id = idx_s[wid][sI];
            tile[wid][sI * 65 + lane] = ftb[(size_t)id * C + lane];  // 256B coalesced
        }
    } else {
        const float* fb = feat + (size_t)b * C * N;
        for (int sI = 0; sI < S; ++sI) {
            const int id = idx_s[wid][sI];
            tile[wid][sI * 65 + lane] = fb[(size_t)lane * N + id];   // scattered fallback
        }
    }
    __syncthreads();

    // grouped_features: (B,C,Q,S), write coalesced (32 consecutive s per c)
    float* out1 = out + (size_t)B * 3 * Q * S;
    const int sI = lane & 31;
    const int ch = lane >> 5;
#pragma unroll
    for (int i = 0; i < 32; ++i) {
        const int c = i * 2 + ch;
        out1[(((size_t)b * C + c) * Q + q) * S + sI] = tile[wid][sI * 65 + c];
    }
}

extern "C" void kernel_launch(void* const* d_in, const int* in_sizes, int n_in,
                              void* d_out, int out_size, void* d_ws, size_t ws_size,
                              hipStream_t stream) {
    const float* q_xyz = (const float*)d_in[0];   // (B,Q,3)
    const float* s_xyz = (const float*)d_in[1];   // (B,N,3)
    const float* feat  = (const float*)d_in[2];   // (B,C,N)
    float* out = (float*)d_out;

    const size_t need = (size_t)B * N * C * sizeof(float);
    if (ws_size >= need) {
        float* ft = (float*)d_ws;
        transpose_feat<<<B * (N / 64), 256, 0, stream>>>(feat, ft);
        ballgroup<true><<<(B * Q) / 4, 256, 0, stream>>>(q_xyz, s_xyz, feat, ft, out);
    } else {
        ballgroup<false><<<(B * Q) / 4, 256, 0, stream>>>(q_xyz, s_xyz, feat, nullptr, out);
    }
}

// Round 4
// 159.512 us; speedup vs baseline: 4.1315x; 4.1315x over previous
//
#include <hip/hip_runtime.h>

// Problem constants (fixed by reference setup_inputs)
constexpr int B = 4, N = 16384, Q = 4096, C = 64, S = 32;

// Kernel 1: transpose features (B,C,N) -> (B,N,C) so per-sample gathers are contiguous.
// ft crosses a kernel boundary under graph replay with non-coherent per-XCD L2s
// (Guideline 16): write it with device-scope (agent) stores so the data lands at the
// coherence point, plus one end-of-kernel fence as insurance. The consumer reads ft
// with device-scope loads — no blanket L2 invalidate anywhere in the hot kernel.
__global__ __launch_bounds__(256) void transpose_feat(const float* __restrict__ f,
                                                      float* __restrict__ ft) {
    __shared__ float tile[64 * 65];
    const int b  = blockIdx.x / (N / 64);
    const int n0 = (blockIdx.x % (N / 64)) * 64;
    const int t  = threadIdx.x;
    const int nl = t & 63;          // local n
    const int cl = t >> 6;          // 0..3
    const float* fb = f + (size_t)b * C * N;
#pragma unroll
    for (int i = 0; i < 16; ++i) {
        int c = i * 4 + cl;
        tile[c * 65 + nl] = fb[(size_t)c * N + n0 + nl];   // 256B coalesced per c
    }
    __syncthreads();
    float* ftb = ft + ((size_t)b * N + n0) * C;
    const int co = t & 63;
#pragma unroll
    for (int i = 0; i < 16; ++i) {
        int n = i * 4 + (t >> 6);
        // device-scope store: visible at the coherence point, not just local L2
        __hip_atomic_store(&ftb[(size_t)n * C + co], tile[co * 65 + n],
                           __ATOMIC_RELAXED, __HIP_MEMORY_SCOPE_AGENT);
    }
    __threadfence();   // release insurance, cost confined to this small kernel
}

// Kernel 2: one wave (64 lanes) per query. Phase 1: ordered ballot ball-query with
// FLOAT64 membership decision (proven bit-exact vs the harness numpy reference).
// Phase 2: gather (ft via device-scope loads) + coalesced writes of both outputs.
template <bool USE_T>
__global__ __launch_bounds__(256) void ballgroup(const float* __restrict__ q_xyz,
                                                 const float* __restrict__ s_xyz,
                                                 const float* __restrict__ feat,
                                                 const float* __restrict__ feat_t,
                                                 float* __restrict__ out) {
    __shared__ int   idx_s[4][S];
    __shared__ float tile[4][S * 65];

    const int t    = threadIdx.x;
    const int lane = t & 63;
    const int wid  = t >> 6;
    const int gq   = blockIdx.x * 4 + wid;       // global query id, 0..B*Q-1
    const int b    = gq >> 12;                   // Q = 4096
    const int q    = gq & (Q - 1);

    const float* qp = q_xyz + ((size_t)b * Q + q) * 3;
    const float qx = qp[0], qy = qp[1], qz = qp[2];
    const double qxd = (double)qx, qyd = (double)qy, qzd = (double)qz;
    const double R2D = 0.2 * 0.2;   // IEEE double product = python's radius*radius

    const float* sb = s_xyz + (size_t)b * N * 3;

    int cnt = 0;                                            // wave-uniform
    for (int base = 0; base < N && cnt < S; base += 64) {
        const int n = base + lane;
        const double dx = (double)sb[n * 3 + 0] - qxd;
        const double dy = (double)sb[n * 3 + 1] - qyd;
        const double dz = (double)sb[n * 3 + 2] - qzd;
        const double d2 = dx * dx + dy * dy + dz * dz;      // exact to ~1e-16
        const bool in = d2 < R2D;
        const unsigned long long m = __ballot(in);
        if (in) {
            const int pos = cnt + __popcll(m & ((1ull << lane) - 1ull));
            if (pos < S) idx_s[wid][pos] = n;
        }
        cnt += __popcll(m);
    }
    if (cnt > S) cnt = S;

    __syncthreads();
    const int idx0 = (cnt > 0) ? idx_s[wid][0] : 0;
    if (lane < S && lane >= cnt) idx_s[wid][lane] = idx0;  // pad with first found (or 0)
    __syncthreads();

    // grouped_xyz: (B,3,Q,S) = support[idx] - query  (single f32 sub: bit-exact)
    for (int e = lane; e < 3 * S; e += 64) {
        const int c  = e >> 5;
        const int sI = e & 31;
        const int id = idx_s[wid][sI];
        out[(((size_t)b * 3 + c) * Q + q) * S + sI] = sb[id * 3 + c] - qp[c];
    }

    // gather feature rows into LDS tile (tile[s][c], stride 65: conflict-free)
    if (USE_T) {
        const float* ftb = feat_t + (size_t)b * N * C;
        for (int sI = 0; sI < S; ++sI) {
            const int id = idx_s[wid][sI];
            // device-scope load: served from the coherence point, never a stale
            // local-L2 line (the graph-replay poison hazard from round 2)
            tile[wid][sI * 65 + lane] =
                __hip_atomic_load(&ftb[(size_t)id * C + lane],
                                  __ATOMIC_RELAXED, __HIP_MEMORY_SCOPE_AGENT);
        }
    } else {
        const float* fb = feat + (size_t)b * C * N;
        for (int sI = 0; sI < S; ++sI) {
            const int id = idx_s[wid][sI];
            tile[wid][sI * 65 + lane] = fb[(size_t)lane * N + id];   // scattered fallback
        }
    }
    __syncthreads();

    // grouped_features: (B,C,Q,S), write coalesced (32 consecutive s per c)
    float* out1 = out + (size_t)B * 3 * Q * S;
    const int sI = lane & 31;
    const int ch = lane >> 5;
#pragma unroll
    for (int i = 0; i < 32; ++i) {
        const int c = i * 2 + ch;
        out1[(((size_t)b * C + c) * Q + q) * S + sI] = tile[wid][sI * 65 + c];
    }
}

extern "C" void kernel_launch(void* const* d_in, const int* in_sizes, int n_in,
                              void* d_out, int out_size, void* d_ws, size_t ws_size,
                              hipStream_t stream) {
    const float* q_xyz = (const float*)d_in[0];   // (B,Q,3)
    const float* s_xyz = (const float*)d_in[1];   // (B,N,3)
    const float* feat  = (const float*)d_in[2];   // (B,C,N)
    float* out = (float*)d_out;

    const size_t need = (size_t)B * N * C * sizeof(float);
    if (ws_size >= need) {
        float* ft = (float*)d_ws;
        transpose_feat<<<B * (N / 64), 256, 0, stream>>>(feat, ft);
        ballgroup<true><<<(B * Q) / 4, 256, 0, stream>>>(q_xyz, s_xyz, feat, ft, out);
    } else {
        ballgroup<false><<<(B * Q) / 4, 256, 0, stream>>>(q_xyz, s_xyz, feat, nullptr, out);
    }
}

// Round 5
// 120.435 us; speedup vs baseline: 5.4720x; 1.3245x over previous
//
#include <hip/hip_runtime.h>

// Problem constants (fixed by reference setup_inputs)
constexpr int B = 4, N = 16384, Q = 4096, C = 64, S = 32;
constexpr int TS = 67;   // LDS tile row stride (floats): (3*s+c)%32 spreads banks

typedef float f32x4 __attribute__((ext_vector_type(4)));

// Kernel 1: transpose features (B,C,N) -> (B,N,C). ft crosses a kernel boundary
// under graph replay with non-coherent per-XCD L2s (Guideline 16): agent-scope
// stores land the data at the coherence point; trailing fence as insurance.
// (Proven correct + passing in round 4 — unchanged.)
__global__ __launch_bounds__(256) void transpose_feat(const float* __restrict__ f,
                                                      float* __restrict__ ft) {
    __shared__ float tile[64 * 65];
    const int b  = blockIdx.x / (N / 64);
    const int n0 = (blockIdx.x % (N / 64)) * 64;
    const int t  = threadIdx.x;
    const int nl = t & 63;
    const int cl = t >> 6;
    const float* fb = f + (size_t)b * C * N;
#pragma unroll
    for (int i = 0; i < 16; ++i) {
        int c = i * 4 + cl;
        tile[c * 65 + nl] = fb[(size_t)c * N + n0 + nl];
    }
    __syncthreads();
    float* ftb = ft + ((size_t)b * N + n0) * C;
    const int co = t & 63;
#pragma unroll
    for (int i = 0; i < 16; ++i) {
        int n = i * 4 + (t >> 6);
        __hip_atomic_store(&ftb[(size_t)n * C + co], tile[co * 65 + n],
                           __ATOMIC_RELAXED, __HIP_MEMORY_SCOPE_AGENT);
    }
    __threadfence();
}

// Kernel 2: one wave per query; 4 independent waves per block, NO __syncthreads
// (all LDS is per-wave). Phase 1: ordered ballot ball-query, f64 decision (proven
// bit-exact). Phase 2: issue 8 cache-bypassing dwordx4 gather loads up-front,
// overlap with the xyz output, drain with counted vmcnt, two 16-row LDS passes.
template <bool USE_T>
__global__ __launch_bounds__(256) void ballgroup(const float* __restrict__ q_xyz,
                                                 const float* __restrict__ s_xyz,
                                                 const float* __restrict__ feat,
                                                 const float* __restrict__ feat_t,
                                                 float* __restrict__ out) {
    __shared__ int   idx_s[4][S];
    __shared__ float tile[4][16 * TS];   // 16-row half-tile per wave (double pass)

    const int t    = threadIdx.x;
    const int lane = t & 63;
    const int wid  = t >> 6;
    const int gq   = blockIdx.x * 4 + wid;
    const int b    = gq >> 12;                   // Q = 4096
    const int q    = gq & (Q - 1);

    const float* qp = q_xyz + ((size_t)b * Q + q) * 3;
    const float qx = qp[0], qy = qp[1], qz = qp[2];
    const double qxd = (double)qx, qyd = (double)qy, qzd = (double)qz;
    const double R2D = 0.2 * 0.2;   // IEEE double product = python's radius*radius

    const float* sb = s_xyz + (size_t)b * N * 3;

    int cnt = 0;                                            // wave-uniform
    for (int base = 0; base < N && cnt < S; base += 64) {
        const int n = base + lane;
        const double dx = (double)sb[n * 3 + 0] - qxd;
        const double dy = (double)sb[n * 3 + 1] - qyd;
        const double dz = (double)sb[n * 3 + 2] - qzd;
        const double d2 = dx * dx + dy * dy + dz * dz;      // exact to ~1e-16
        const bool in = d2 < R2D;
        const unsigned long long m = __ballot(in);
        if (in) {
            const int pos = cnt + __popcll(m & ((1ull << lane) - 1ull));
            if (pos < S) idx_s[wid][pos] = n;
        }
        cnt += __popcll(m);
    }
    if (cnt > S) cnt = S;

    const int idx0 = (cnt > 0) ? idx_s[wid][0] : 0;
    if (lane < S && lane >= cnt) idx_s[wid][lane] = idx0;  // pad (same-wave: no sync)

    const int sub  = lane >> 4;          // 0..3 : row-within-quad
    const int cq   = (lane & 15) * 4;    // col start (floats)
    const int chi  = lane >> 4;          // 0..3 : c offset for out phase
    const int sI16 = lane & 15;          // s within 16-row pass
    float* out1 = out + (size_t)B * 3 * Q * S;

    if (USE_T) {
        // Issue all 8 gather loads (rows j*4+sub), device-coherent (bypass L1+L2:
        // same semantics as the proven agent-scope atomic loads, but 16B wide).
        const float* ftb = feat_t + (size_t)b * N * C;
        f32x4 v[8];
#pragma unroll
        for (int j = 0; j < 8; ++j) {
            const int id = idx_s[wid][j * 4 + sub];
            const float* p = ftb + ((size_t)id << 6) + cq;
            asm volatile("global_load_dwordx4 %0, %1, off sc0 sc1"
                         : "=v"(v[j]) : "v"(p));
        }

        // grouped_xyz overlaps the gather latency: (B,3,Q,S) = support[idx]-query
        for (int e = lane; e < 3 * S; e += 64) {
            const int c  = e >> 5;
            const int sI = e & 31;
            const int id = idx_s[wid][sI];
            out[(((size_t)b * 3 + c) * Q + q) * S + sI] = sb[id * 3 + c] - qp[c];
        }

        // Loads 0..3 retired when <=4 outstanding (loads 4..7 are always younger).
        asm volatile("s_waitcnt vmcnt(4)" ::: "memory");
        __builtin_amdgcn_sched_barrier(0);
#pragma unroll
        for (int j = 0; j < 4; ++j) {
            const int r = j * 4 + sub;
#pragma unroll
            for (int k = 0; k < 4; ++k)
                tile[wid][r * TS + cq + k] = v[j][k];
        }
#pragma unroll
        for (int i = 0; i < 16; ++i) {   // write out s = 0..15 for all c
            const int c = i * 4 + chi;
            out1[(((size_t)b * C + c) * Q + q) * S + sI16] = tile[wid][sI16 * TS + c];
        }

        // Loads 4..7 retired: >=20 younger vmem ops (xyz + 16 stores) issued since.
        asm volatile("s_waitcnt vmcnt(8)" ::: "memory");
        __builtin_amdgcn_sched_barrier(0);
#pragma unroll
        for (int j = 0; j < 4; ++j) {
            const int r = j * 4 + sub;
#pragma unroll
            for (int k = 0; k < 4; ++k)
                tile[wid][r * TS + cq + k] = v[4 + j][k];
        }
#pragma unroll
        for (int i = 0; i < 16; ++i) {   // write out s = 16..31 for all c
            const int c = i * 4 + chi;
            out1[(((size_t)b * C + c) * Q + q) * S + 16 + sI16] = tile[wid][sI16 * TS + c];
        }
    } else {
        // Fallback (no workspace): scattered reads from original layout.
        for (int e = lane; e < 3 * S; e += 64) {
            const int c  = e >> 5;
            const int sI = e & 31;
            const int id = idx_s[wid][sI];
            out[(((size_t)b * 3 + c) * Q + q) * S + sI] = sb[id * 3 + c] - qp[c];
        }
        const float* fb = feat + (size_t)b * C * N;
        for (int p = 0; p < 2; ++p) {
            for (int s2 = 0; s2 < 16; ++s2) {
                const int id = idx_s[wid][p * 16 + s2];
                tile[wid][s2 * TS + lane] = fb[(size_t)lane * N + id];
            }
#pragma unroll
            for (int i = 0; i < 16; ++i) {
                const int c = i * 4 + chi;
                out1[(((size_t)b * C + c) * Q + q) * S + p * 16 + sI16] =
                    tile[wid][sI16 * TS + c];
            }
        }
    }
}

extern "C" void kernel_launch(void* const* d_in, const int* in_sizes, int n_in,
                              void* d_out, int out_size, void* d_ws, size_t ws_size,
                              hipStream_t stream) {
    const float* q_xyz = (const float*)d_in[0];   // (B,Q,3)
    const float* s_xyz = (const float*)d_in[1];   // (B,N,3)
    const float* feat  = (const float*)d_in[2];   // (B,C,N)
    float* out = (float*)d_out;

    const size_t need = (size_t)B * N * C * sizeof(float);
    if (ws_size >= need) {
        float* ft = (float*)d_ws;
        transpose_feat<<<B * (N / 64), 256, 0, stream>>>(feat, ft);
        ballgroup<true><<<(B * Q) / 4, 256, 0, stream>>>(q_xyz, s_xyz, feat, ft, out);
    } else {
        ballgroup<false><<<(B * Q) / 4, 256, 0, stream>>>(q_xyz, s_xyz, feat, nullptr, out);
    }
}

// Round 6
// 76.959 us; speedup vs baseline: 8.5633x; 1.5649x over previous
//
#include <hip/hip_runtime.h>

// Problem constants (fixed by reference setup_inputs)
constexpr int B = 4, N = 16384, Q = 4096, C = 64, S = 32;
constexpr int TS = 67;            // LDS tile row stride (floats); 67%32=3 spreads banks
constexpr int TGRID = B * (N / 64);   // 1024 transpose-role blocks
constexpr int QBLKS = (B * Q) / 4;    // 4096 query/group blocks (4 waves each)

typedef float f32x4 __attribute__((ext_vector_type(4)));

// ---------------------------------------------------------------------------
// Kernel 1 "prep": two roles selected by blockIdx.
//  role T (blocks [0,1024)): transpose features (B,C,N)->(B,N,C) into ws.
//  role A (blocks [1024,1024+4096)): ball query, one wave per query, f64
//    decision (proven bit-exact vs harness reference), software-pipelined scan;
//    writes padded idx (u16) to ws.
//  All cross-kernel data (ft, idx) is written with device-scope (sc1) stores —
//  visible at the coherence point without any __threadfence (whose buffer_inv
//  side thrashed L2 in round 3).
// ---------------------------------------------------------------------------
__global__ __launch_bounds__(256) void prep(const float* __restrict__ q_xyz,
                                            const float* __restrict__ s_xyz,
                                            const float* __restrict__ f,
                                            float* __restrict__ ft,
                                            unsigned short* __restrict__ idxb) {
    const int t = threadIdx.x;
    if ((int)blockIdx.x < TGRID) {
        // ---- transpose role ----
        __shared__ float tile[64 * 65];
        const int b  = blockIdx.x >> 8;          // N/64 = 256 blocks per batch
        const int n0 = (blockIdx.x & 255) * 64;
        const int nl = t & 63;
        const int cl = t >> 6;
        const float* fb = f + (size_t)b * C * N;
#pragma unroll
        for (int i = 0; i < 16; ++i) {
            const int c = i * 4 + cl;
            tile[c * 65 + nl] = fb[(size_t)c * N + n0 + nl];   // 256B coalesced per c
        }
        __syncthreads();
        float* ftb = ft + ((size_t)b * N + n0) * C;
        const int l15 = t & 15;
        const int nw  = t >> 4;                   // 0..15
#pragma unroll
        for (int it = 0; it < 4; ++it) {
            const int n = it * 16 + nw;
            f32x4 v;
#pragma unroll
            for (int k = 0; k < 4; ++k) v[k] = tile[(4 * l15 + k) * 65 + n];
            float* p = ftb + (size_t)n * C + 4 * l15;
            // device-coherent write-through store (16B): lands at L3
            asm volatile("global_store_dwordx4 %0, %1, off sc0 sc1"
                         :: "v"(p), "v"(v) : "memory");
        }
    } else {
        // ---- query role: one wave per query ----
        __shared__ int idx_s[4][S];
        const int lane = t & 63;
        const int wid  = t >> 6;
        const int gq   = ((int)blockIdx.x - TGRID) * 4 + wid;   // 0..B*Q-1
        const int b    = gq >> 12;                              // Q = 4096
        const float* qp = q_xyz + (size_t)gq * 3;
        const double qxd = (double)qp[0], qyd = (double)qp[1], qzd = (double)qp[2];
        const double R2D = 0.2 * 0.2;   // IEEE double = python's radius*radius
        const float* sb = s_xyz + (size_t)b * N * 3;

        int cnt = 0;                                            // wave-uniform
        float sx = sb[lane * 3 + 0], sy = sb[lane * 3 + 1], sz = sb[lane * 3 + 2];
        for (int base = 0; base < N && cnt < S; base += 64) {
            // prefetch next chunk while computing current (hides L1/L2 latency)
            float nx = sx, ny = sy, nz = sz;
            if (base + 64 < N) {
                const int nn = (base + 64 + lane) * 3;
                nx = sb[nn + 0]; ny = sb[nn + 1]; nz = sb[nn + 2];
            }
            const double dx = (double)sx - qxd;
            const double dy = (double)sy - qyd;
            const double dz = (double)sz - qzd;
            const bool in = (dx * dx + dy * dy + dz * dz) < R2D;  // exact f64 decision
            const unsigned long long m = __ballot(in);
            if (in) {
                const int pos = cnt + __popcll(m & ((1ull << lane) - 1ull));
                if (pos < S) idx_s[wid][pos] = base + lane;
            }
            cnt += __popcll(m);
            sx = nx; sy = ny; sz = nz;
        }
        if (cnt > S) cnt = S;
        const int idx0 = (cnt > 0) ? idx_s[wid][0] : 0;
        if (lane < S) {
            const int v = (lane < cnt) ? idx_s[wid][lane] : idx0;  // pad w/ first found
            __hip_atomic_store(&idxb[(size_t)gq * S + lane], (unsigned short)v,
                               __ATOMIC_RELAXED, __HIP_MEMORY_SCOPE_AGENT);
        }
    }
}

// ---------------------------------------------------------------------------
// Kernel 2 "group": uniform gather+write, one wave per query (no tail).
// idx via agent loads, ft via sc0sc1 dwordx4 (both bypass possibly-stale L2).
// ---------------------------------------------------------------------------
__global__ __launch_bounds__(256) void group(const float* __restrict__ q_xyz,
                                             const float* __restrict__ s_xyz,
                                             const float* __restrict__ ft,
                                             const unsigned short* __restrict__ idxb,
                                             float* __restrict__ out) {
    __shared__ int   idx_s[4][S];
    __shared__ float tile[4][16 * TS];   // 16-row half-tile per wave (double pass)

    const int t    = threadIdx.x;
    const int lane = t & 63;
    const int wid  = t >> 6;
    const int gq   = blockIdx.x * 4 + wid;
    const int b    = gq >> 12;
    const int q    = gq & (Q - 1);

    if (lane < S) {
        const unsigned short v =
            __hip_atomic_load(&idxb[(size_t)gq * S + lane],
                              __ATOMIC_RELAXED, __HIP_MEMORY_SCOPE_AGENT);
        idx_s[wid][lane] = (int)v;
    }

    const float* qp = q_xyz + (size_t)gq * 3;
    const float* sb = s_xyz + (size_t)b * N * 3;
    const int sub  = lane >> 4;          // 0..3
    const int cq   = (lane & 15) * 4;    // col start (floats)
    const int chi  = lane >> 4;
    const int sI16 = lane & 15;
    float* out1 = out + (size_t)B * 3 * Q * S;
    const float* ftb = ft + (size_t)b * N * C;

    // issue all 8 gather loads up-front (L3-coherent, bypass stale L2)
    f32x4 v[8];
#pragma unroll
    for (int j = 0; j < 8; ++j) {
        const int id = idx_s[wid][j * 4 + sub];
        const float* p = ftb + ((size_t)id << 6) + cq;
        asm volatile("global_load_dwordx4 %0, %1, off sc0 sc1"
                     : "=v"(v[j]) : "v"(p));
    }

    // grouped_xyz overlaps the gather latency: (B,3,Q,S) = support[idx]-query
    for (int e = lane; e < 3 * S; e += 64) {
        const int c  = e >> 5;
        const int sI = e & 31;
        const int id = idx_s[wid][sI];
        out[(((size_t)b * 3 + c) * Q + q) * S + sI] = sb[id * 3 + c] - qp[c];
    }

    // loads 0..3 retired once <=4 vmem ops outstanding (in-order retire; any
    // compiler-issued xyz ops only make the wait stricter).
    asm volatile("s_waitcnt vmcnt(4)" ::: "memory");
    __builtin_amdgcn_sched_barrier(0);
#pragma unroll
    for (int j = 0; j < 4; ++j) {
        const int r = j * 4 + sub;
#pragma unroll
        for (int k = 0; k < 4; ++k)
            tile[wid][r * TS + cq + k] = v[j][k];
    }
#pragma unroll
    for (int i = 0; i < 16; ++i) {       // write out s = 0..15 for all c
        const int c = i * 4 + chi;
        out1[(((size_t)b * C + c) * Q + q) * S + sI16] = tile[wid][sI16 * TS + c];
    }

    asm volatile("s_waitcnt vmcnt(8)" ::: "memory");   // loads 4..7 retired
    __builtin_amdgcn_sched_barrier(0);
#pragma unroll
    for (int j = 0; j < 4; ++j) {
        const int r = j * 4 + sub;
#pragma unroll
        for (int k = 0; k < 4; ++k)
            tile[wid][r * TS + cq + k] = v[4 + j][k];
    }
#pragma unroll
    for (int i = 0; i < 16; ++i) {       // write out s = 16..31 for all c
        const int c = i * 4 + chi;
        out1[(((size_t)b * C + c) * Q + q) * S + 16 + sI16] = tile[wid][sI16 * TS + c];
    }
}

// ---------------------------------------------------------------------------
// Fallback (ws too small): round-5's fused single kernel, original layout.
// ---------------------------------------------------------------------------
__global__ __launch_bounds__(256) void ballgroup_fb(const float* __restrict__ q_xyz,
                                                    const float* __restrict__ s_xyz,
                                                    const float* __restrict__ feat,
                                                    float* __restrict__ out) {
    __shared__ int   idx_s[4][S];
    __shared__ float tile[4][16 * TS];
    const int t = threadIdx.x, lane = t & 63, wid = t >> 6;
    const int gq = blockIdx.x * 4 + wid;
    const int b = gq >> 12, q = gq & (Q - 1);
    const float* qp = q_xyz + (size_t)gq * 3;
    const double qxd = (double)qp[0], qyd = (double)qp[1], qzd = (double)qp[2];
    const double R2D = 0.2 * 0.2;
    const float* sb = s_xyz + (size_t)b * N * 3;
    int cnt = 0;
    for (int base = 0; base < N && cnt < S; base += 64) {
        const int n = base + lane;
        const double dx = (double)sb[n * 3 + 0] - qxd;
        const double dy = (double)sb[n * 3 + 1] - qyd;
        const double dz = (double)sb[n * 3 + 2] - qzd;
        const bool in = (dx * dx + dy * dy + dz * dz) < R2D;
        const unsigned long long m = __ballot(in);
        if (in) {
            const int pos = cnt + __popcll(m & ((1ull << lane) - 1ull));
            if (pos < S) idx_s[wid][pos] = n;
        }
        cnt += __popcll(m);
    }
    if (cnt > S) cnt = S;
    const int idx0 = (cnt > 0) ? idx_s[wid][0] : 0;
    if (lane < S && lane >= cnt) idx_s[wid][lane] = idx0;
    for (int e = lane; e < 3 * S; e += 64) {
        const int c = e >> 5, sI = e & 31;
        const int id = idx_s[wid][sI];
        out[(((size_t)b * 3 + c) * Q + q) * S + sI] = sb[id * 3 + c] - qp[c];
    }
    float* out1 = out + (size_t)B * 3 * Q * S;
    const int chi = lane >> 4, sI16 = lane & 15;
    const float* fb = feat + (size_t)b * C * N;
    for (int p = 0; p < 2; ++p) {
        for (int s2 = 0; s2 < 16; ++s2) {
            const int id = idx_s[wid][p * 16 + s2];
            tile[wid][s2 * TS + lane] = fb[(size_t)lane * N + id];
        }
#pragma unroll
        for (int i = 0; i < 16; ++i) {
            const int c = i * 4 + chi;
            out1[(((size_t)b * C + c) * Q + q) * S + p * 16 + sI16] =
                tile[wid][sI16 * TS + c];
        }
    }
}

extern "C" void kernel_launch(void* const* d_in, const int* in_sizes, int n_in,
                              void* d_out, int out_size, void* d_ws, size_t ws_size,
                              hipStream_t stream) {
    const float* q_xyz = (const float*)d_in[0];   // (B,Q,3)
    const float* s_xyz = (const float*)d_in[1];   // (B,N,3)
    const float* feat  = (const float*)d_in[2];   // (B,C,N)
    float* out = (float*)d_out;

    const size_t ftBytes  = (size_t)B * N * C * sizeof(float);       // 16 MB
    const size_t idxBytes = (size_t)B * Q * S * sizeof(unsigned short); // 1 MB
    if (ws_size >= ftBytes + idxBytes) {
        float* ft = (float*)d_ws;
        unsigned short* idxb = (unsigned short*)((char*)d_ws + ftBytes);
        prep<<<TGRID + QBLKS, 256, 0, stream>>>(q_xyz, s_xyz, feat, ft, idxb);
        group<<<QBLKS, 256, 0, stream>>>(q_xyz, s_xyz, ft, idxb, out);
    } else {
        ballgroup_fb<<<QBLKS, 256, 0, stream>>>(q_xyz, s_xyz, feat, out);
    }
}